// Round 8
// baseline (124.814 us; speedup 1.0000x reference)
//
#include <hip/hip_runtime.h>
#include <hip/hip_bf16.h>
#include <stdint.h>

typedef __bf16 bf16x8 __attribute__((ext_vector_type(8)));
typedef float  f32x4  __attribute__((ext_vector_type(4)));

static constexpr int Mdim = 2048;   // B*S
static constexpr int Ndim = 4096;   // O
static constexpr int Kdim = 4096;   // I = G*A
static constexpr int DQ_BLOCKS = (Ndim * Kdim / 8) / 256;        // 8192
static constexpr int CVT_BLOCKS = (Mdim * Kdim / 8) / 256;       // 4096

// ---------------- fused prep: dequant W -> bf16 [O][K] (LDS-bounced coalesced
// binary reads), cast X -> bf16 [M][K]
__global__ __launch_bounds__(256)
void prep(const float* __restrict__ binary, const float* __restrict__ alpha,
          const float* __restrict__ x, __bf16* __restrict__ w,
          __bf16* __restrict__ xb) {
  __shared__ float ls[6144];   // 24 KB binary chunk
  const int b = blockIdx.x;
  const int t = threadIdx.x;
  if (b < DQ_BLOCKS) {
    // 1) coalesced load: block chunk = 2048 weights = 6144 floats = 24 KB,
    //    unit-stride float4 across threads (wave = 4 KB contiguous / step)
    const float* src = binary + (long)b * 6144;
#pragma unroll
    for (int j = 0; j < 6; ++j) {
      float4 v = *(const float4*)(src + (j * 256 + t) * 4);
      *(float4*)(ls + (j * 256 + t) * 4) = v;
    }
    __syncthreads();
    // 2) private 96 B from LDS (16B-aligned; ~2-way bank alias = free)
    long e = ((long)b * 256 + t) * 8;       // 8 weights/thread
    int o = (int)(e >> 12);
    int g = (int)((e & 4095) >> 7);
    const float* al = alpha + ((long)o * 32 + g) * 3;
    float a0 = al[0], a1 = al[1], a2 = al[2];
    const float* q = ls + t * 24;
    bf16x8 wv;
#pragma unroll
    for (int k = 0; k < 8; ++k)
      wv[k] = (__bf16)(a0 * q[k * 3] + a1 * q[k * 3 + 1] + a2 * q[k * 3 + 2]);
    *(bf16x8*)(w + e) = wv;
  } else {
    long e = ((long)(b - DQ_BLOCKS) * 256 + t) * 8;
    float4 v0 = *(const float4*)(x + e);
    float4 v1 = *(const float4*)(x + e + 4);
    bf16x8 r;
    r[0] = (__bf16)v0.x; r[1] = (__bf16)v0.y; r[2] = (__bf16)v0.z; r[3] = (__bf16)v0.w;
    r[4] = (__bf16)v1.x; r[5] = (__bf16)v1.y; r[6] = (__bf16)v1.z; r[7] = (__bf16)v1.w;
    *(bf16x8*)(xb + e) = r;
  }
}

// ---------------- split-K reduce: out = P0 + P1 + bias  (bf16 partials)
__global__ __launch_bounds__(256)
void reduce_add(const __bf16* __restrict__ p, const float* __restrict__ bias,
                float* __restrict__ out) {
  long e = ((long)blockIdx.x * 256 + threadIdx.x) * 8;
  bf16x8 a = *(const bf16x8*)(p + e);
  bf16x8 c = *(const bf16x8*)(p + (long)Mdim * Ndim + e);
  int col = (int)(e & (Ndim - 1));
  float4 bv0 = *(const float4*)(bias + col);
  float4 bv1 = *(const float4*)(bias + col + 4);
  float4 r0, r1;
  r0.x = (float)a[0] + (float)c[0] + bv0.x;
  r0.y = (float)a[1] + (float)c[1] + bv0.y;
  r0.z = (float)a[2] + (float)c[2] + bv0.z;
  r0.w = (float)a[3] + (float)c[3] + bv0.w;
  r1.x = (float)a[4] + (float)c[4] + bv1.x;
  r1.y = (float)a[5] + (float)c[5] + bv1.y;
  r1.z = (float)a[6] + (float)c[6] + bv1.z;
  r1.w = (float)a[7] + (float)c[7] + bv1.w;
  *(float4*)(out + e) = r0;
  *(float4*)(out + e + 4) = r1;
}

// ---------------- 256x256 split-K=2 GEMM, 8 waves (2Mx4N, wave 128x64),
// BK=64, double-buffered LDS (128KB), 8 phases / 2 tiles, GATE(8) steady.
static constexpr int KSLICE = 2048;
static constexpr int NT = KSLICE / 64;   // 32 K-tiles per slice
static constexpr int HB = 65536;         // bytes per buffer (A 32KB + B 32KB)

__device__ __forceinline__ void g2l16(const void* g, void* l) {
  __builtin_amdgcn_global_load_lds(
      (const __attribute__((address_space(1))) void*)g,
      (__attribute__((address_space(3))) void*)l, 16, 0, 0);
}

#define BAR()    __builtin_amdgcn_s_barrier()
#define LGKM0()  asm volatile("s_waitcnt lgkmcnt(0)" ::: "memory")
#define SCHED0() __builtin_amdgcn_sched_barrier(0)
#define GATE8()  asm volatile("s_waitcnt vmcnt(8)" ::: "memory")
#define GATE0()  asm volatile("s_waitcnt vmcnt(0)" ::: "memory")

// Stage units (2 x g2l16 each).  LDS linear dest (wave-uniform base + lane*16);
// global source pre-swizzled (granule ^= row&7) so read-side XOR matches. [rule 21]
#define STAGE_A1(t, bo) do { \
  g2l16(baseA +                 (long)(t) * 64, sm + (bo) +     0 + w * 1024); \
  g2l16(baseA + 128L * Kdim   + (long)(t) * 64, sm + (bo) + 16384 + w * 1024); \
} while (0)
#define STAGE_A2(t, bo) do { \
  g2l16(baseA +  64L * Kdim   + (long)(t) * 64, sm + (bo) +  8192 + w * 1024); \
  g2l16(baseA + 192L * Kdim   + (long)(t) * 64, sm + (bo) + 24576 + w * 1024); \
} while (0)
#define STAGE_B1(t, bo) do { \
  g2l16(baseB +                 (long)(t) * 64, sm + (bo) + 32768 + bq * 1024); \
  g2l16(baseB +   8L * Kdim   + (long)(t) * 64, sm + (bo) + 32768 + bq * 1024 + 1024); \
} while (0)
#define STAGE_B2(t, bo) do { \
  g2l16(baseB +  32L * Kdim   + (long)(t) * 64, sm + (bo) + 32768 + bq * 1024 + 4096); \
  g2l16(baseB +  40L * Kdim   + (long)(t) * 64, sm + (bo) + 32768 + bq * 1024 + 5120); \
} while (0)

#define LOAD_A4(dst, bo, m0_) do { \
  _Pragma("unroll") for (int m_ = 0; m_ < 4; ++m_) \
    _Pragma("unroll") for (int h_ = 0; h_ < 2; ++h_) \
      dst[m_][h_] = *(const bf16x8*)(sm + (bo) + aoffbase + ((m0_) + m_) * 2048 + swz[h_]); \
} while (0)
#define LOAD_B2(dst, bo, n0_) do { \
  _Pragma("unroll") for (int n_ = 0; n_ < 2; ++n_) \
    _Pragma("unroll") for (int h_ = 0; h_ < 2; ++h_) \
      dst[n_][h_] = *(const bf16x8*)(sm + (bo) + boffbase + ((n0_) + n_) * 2048 + swz[h_]); \
} while (0)

#define MMA8(fa_, fb_, m0_, n0_) do { \
  __builtin_amdgcn_s_setprio(1); \
  _Pragma("unroll") for (int m_ = 0; m_ < 4; ++m_) \
    _Pragma("unroll") for (int n_ = 0; n_ < 2; ++n_) { \
      acc[(m0_) + m_][(n0_) + n_] = __builtin_amdgcn_mfma_f32_16x16x32_bf16( \
          fa_[m_][0], fb_[n_][0], acc[(m0_) + m_][(n0_) + n_], 0, 0, 0); \
      acc[(m0_) + m_][(n0_) + n_] = __builtin_amdgcn_mfma_f32_16x16x32_bf16( \
          fa_[m_][1], fb_[n_][1], acc[(m0_) + m_][(n0_) + n_], 0, 0, 0); \
    } \
  __builtin_amdgcn_s_setprio(0); \
} while (0)

#define KTILE(t_, bo, PF_, LASTGATE) do { \
  /* P1 */ \
  LOAD_A4(fa, bo, 0); LOAD_B2(fb01, bo, 0); \
  BAR(); LGKM0(); SCHED0(); \
  MMA8(fa, fb01, 0, 0); \
  BAR(); \
  /* P2 */ \
  LOAD_B2(fb23, bo, 2); \
  if (PF_) { STAGE_A1((t_) + 2, bo); STAGE_B1((t_) + 2, bo); } \
  BAR(); LGKM0(); SCHED0(); \
  MMA8(fa, fb23, 0, 2); \
  BAR(); \
  /* P3 */ \
  LOAD_A4(fa, bo, 4); \
  if (PF_) STAGE_B2((t_) + 2, bo); \
  BAR(); LGKM0(); SCHED0(); \
  MMA8(fa, fb01, 4, 0); \
  BAR(); \
  /* P4 */ \
  if (PF_) { STAGE_A2((t_) + 2, bo); GATE8(); } else { LASTGATE; } \
  BAR(); \
  MMA8(fa, fb23, 4, 2); \
  BAR(); \
} while (0)

__global__ __launch_bounds__(512, 2)
void gemm256(const __bf16* __restrict__ A, const __bf16* __restrict__ Bw,
             __bf16* __restrict__ P) {
  __shared__ __align__(128) char sm[2 * HB];   // 128 KB
  const int tid = threadIdx.x, lane = tid & 63, w = tid >> 6;
  const int wm = w >> 2, wn = w & 3;           // wave tile 128x64

  const int bid = blockIdx.x;
  const int logical = (bid & 7) * 32 + (bid >> 3);
  const int ks = logical >> 7;                 // split-K slice
  const int tile = logical & 127;
  const int tm = tile & 7, tn = tile >> 3;     // 8 x 16 tiles of 256x256
  const int kbase = ks * KSLICE;

  __bf16* Pout = P + (long)ks * Mdim * Ndim;

  const int rlo = lane >> 3;
  const int gsw = (lane & 7) ^ rlo;
  const __bf16* baseA = A + (long)(tm * 256 + w * 8 + rlo) * Kdim + kbase + gsw * 8;
  const __bf16* baseB = Bw + (long)(tn * 256 + (w >> 1) * 64 + (w & 1) * 16 + rlo) * Kdim
                        + kbase + gsw * 8;
  const int bq = (w >> 1) * 8 + (w & 1) * 2;

  int swz[2];
#pragma unroll
  for (int h = 0; h < 2; ++h)
    swz[h] = (((h * 4 + (lane >> 4)) ^ (lane & 7)) << 4);
  const int aoffbase = (wm * 128 + (lane & 15)) * 128;
  const int boffbase = 32768 + (wn * 64 + (lane & 15)) * 128;

  f32x4 acc[8][4] = {};
  bf16x8 fa[4][2], fb01[2][2], fb23[2][2];

  STAGE_A1(0, 0);  STAGE_B1(0, 0);  STAGE_B2(0, 0);  STAGE_A2(0, 0);
  STAGE_A1(1, HB); STAGE_B1(1, HB); STAGE_B2(1, HB); STAGE_A2(1, HB);
  GATE8();
  BAR();

  for (int i = 0; i < NT / 2; ++i) {
    const int t0 = 2 * i, t1 = 2 * i + 1;
    const bool pf = (i < NT / 2 - 1);
    KTILE(t0, 0,  pf, GATE0());
    KTILE(t1, HB, pf, GATE0());
  }

  const int r4 = (lane >> 4) * 4;
  const int cl = lane & 15;
#pragma unroll
  for (int m = 0; m < 8; ++m)
#pragma unroll
    for (int n = 0; n < 4; ++n)
#pragma unroll
      for (int r = 0; r < 4; ++r) {
        int row = tm * 256 + wm * 128 + m * 16 + r4 + r;
        int col = tn * 256 + wn * 64 + n * 16 + cl;
        Pout[(long)row * Ndim + col] = (__bf16)acc[m][n][r];
      }
}

extern "C" void kernel_launch(void* const* d_in, const int* in_sizes, int n_in,
                              void* d_out, int out_size, void* d_ws, size_t ws_size,
                              hipStream_t stream) {
  const float* x      = (const float*)d_in[0];
  const float* binary = (const float*)d_in[1];
  const float* alpha  = (const float*)d_in[2];
  const float* bias   = (const float*)d_in[3];
  float* out = (float*)d_out;

  __bf16* wb = (__bf16*)d_ws;                              // 32 MB  W bf16 [N][K]
  __bf16* xb = wb + (size_t)Ndim * Kdim;                   // 16 MB  X bf16 [M][K]
  __bf16* pp = xb + (size_t)Mdim * Kdim;                   // 32 MB  partials bf16 [2][M][N]

  prep<<<dim3(DQ_BLOCKS + CVT_BLOCKS), 256, 0, stream>>>(binary, alpha, x, wb, xb);
  gemm256<<<dim3(256), 512, 0, stream>>>(xb, wb, pp);
  reduce_add<<<dim3(Mdim * Ndim / 8 / 256), 256, 0, stream>>>(pp, bias, out);
}